// Round 8
// baseline (115.743 us; speedup 1.0000x reference)
//
#include <hip/hip_runtime.h>

// MLP3D fused, MI355X gfx950 — round 8.
// vs r7 (50.4 us main, MfmaUtil 32%): register double-buffered B-fragments.
// r7 issued the 8 ds_read_b128 at the top of each kb and consumed them
// immediately -> ~600 cyc unhidden lgkm stall per kb-step (12K cyc/wave).
// Now: B(kb+1) ds_reads + A(kb+3) global loads issue BEFORE the MFMA block
// of kb; 32 MFMAs (~620 cyc issue) cover LDS (~150-250) and L2 (~200-300)
// latency. A uses a 4-buffer rotation so its prefetch has no WAR hazard.
// Register audit: acc128 + A64 + bc64 + bn64 + misc ~= 350 < 512/wave at
// 2 waves/SIMD (lb(256,2)) — watch WRITE_SIZE for spill (r4 lesson).

#define NPTS 131072
#define M_PB 128
#define AST 264   // activation row stride in halves (256+8)

typedef _Float16 half8   __attribute__((ext_vector_type(8)));
typedef _Float16 half4_t __attribute__((ext_vector_type(4)));
typedef __fp16   fp16x2  __attribute__((ext_vector_type(2)));
typedef float    float4_t __attribute__((ext_vector_type(4)));

// ---- prep: W (f32 [K][256]) -> f16 per-wave-contiguous fragment layout ----
// dst[(((s*KB + kb)*4 + tn)*64 + l)*8 + j] = W[(kb*32 + (l>>4)*8 + j)*256 + s*64 + tn*16 + (l&15)]
__global__ void prep(const float* __restrict__ W0, const float* __restrict__ W1,
                     const float* __restrict__ W2, _Float16* __restrict__ ws) {
  int id = blockIdx.x * 256 + threadIdx.x;   // 147456 total
  _Float16 v;
  if (id < 16384) {            // W0sw: 4 slices x 2 kb x 4 tn x 512
    int e = id, j = e & 7, l = (e >> 3) & 63, tn = (e >> 9) & 3, kb = (e >> 11) & 1, s = e >> 12;
    int k = kb * 32 + (l >> 4) * 8 + j, n = s * 64 + tn * 16 + (l & 15);
    v = (k < 63) ? (_Float16)W0[k * 256 + n] : (_Float16)0.f;
  } else if (id < 81920) {     // W1sw: 4 x 8 x 4 x 512
    int e = id - 16384, j = e & 7, l = (e >> 3) & 63, tn = (e >> 9) & 3, kb = (e >> 11) & 7, s = e >> 14;
    int k = kb * 32 + (l >> 4) * 8 + j, n = s * 64 + tn * 16 + (l & 15);
    v = (_Float16)W1[k * 256 + n];
  } else {                     // W2sw
    int e = id - 81920, j = e & 7, l = (e >> 3) & 63, tn = (e >> 9) & 3, kb = (e >> 11) & 7, s = e >> 14;
    int k = kb * 32 + (l >> 4) * 8 + j, n = s * 64 + tn * 16 + (l & 15);
    v = (_Float16)W2[k * 256 + n];
  }
  ws[id] = v;
}

__device__ __forceinline__ half4_t pack4(float a, float b, float cc, float d) {
  fp16x2 p0 = __builtin_amdgcn_cvt_pkrtz(a, b);
  fp16x2 p1 = __builtin_amdgcn_cvt_pkrtz(cc, d);
  half4_t h;
  h[0] = (_Float16)p0[0]; h[1] = (_Float16)p0[1];
  h[2] = (_Float16)p1[0]; h[3] = (_Float16)p1[1];
  return h;
}

__global__ __launch_bounds__(256, 2) void mlp_main(
    const float* __restrict__ coords,
    const _Float16* __restrict__ W0sw,
    const _Float16* __restrict__ W1sw,
    const _Float16* __restrict__ W2sw,
    const float* __restrict__ b0, const float* __restrict__ b1,
    const float* __restrict__ b2,
    const float* __restrict__ Wocc, const float* __restrict__ bocc,
    const float* __restrict__ Wc, const float* __restrict__ bc,
    float* __restrict__ out) {
  __shared__ _Float16 actX[M_PB * AST];   // E -> h -> t1 (one buffer, barriered)
  __shared__ float occ_s[4][M_PB];

  const int t = threadIdx.x;
  const int w = t >> 6;          // wave = neuron slice [64w,64w+64) = part id
  const int l = t & 63;
  const int c = l & 15;
  const int q = l >> 4;
  const int m0 = blockIdx.x * M_PB;

  // ---- positional encoding: 2 threads/point, 32 k-values each ----
  {
    int m = t & 127, kh = (t >> 7) * 32;   // kh wave-uniform
    const float* cp = coords + (size_t)(m0 + m) * 3;
    float x0 = cp[0], x1 = cp[1], x2 = cp[2];
#pragma unroll
    for (int i = 0; i < 4; ++i) {
      float v[8];
#pragma unroll
      for (int u = 0; u < 8; ++u) {
        int k = kh + i * 8 + u;
        float r;
        if (k >= 63) r = 0.f;
        else if (k < 3) r = (k == 0) ? x0 : (k == 1 ? x1 : x2);
        else {
          int kk = k - 3;
          int f = kk / 6;
          int rem = kk - 6 * f;
          int s = (rem >= 3) ? 1 : 0;
          int i3 = rem - 3 * s;
          float xi = (i3 == 0) ? x0 : (i3 == 1 ? x1 : x2);
          float arg = xi * (float)(1 << f);
          float nn = rintf(arg * 0.15915494309189535f);
          float rr = fmaf(nn, -6.28318548202514648f, arg);
          rr = fmaf(nn, 1.7484555e-7f, rr);
          r = s ? __cosf(rr) : __sinf(rr);
        }
        v[u] = r;
      }
      half8 ev;
#pragma unroll
      for (int u = 0; u < 4; ++u) {
        fp16x2 p = __builtin_amdgcn_cvt_pkrtz(v[2 * u], v[2 * u + 1]);
        ev[2 * u] = (_Float16)p[0]; ev[2 * u + 1] = (_Float16)p[1];
      }
      *(half8*)&actX[m * AST + kh + i * 8] = ev;
    }
  }
  __syncthreads();                                   // (1) E ready

  float4_t acc[4][8];
  const _Float16* ap = actX + c * AST + q * 8;

  // ---- layer 0: h = E @ W0 + b0 (no relu), K=64: all A and B upfront ----
  {
    const _Float16* wb = W0sw + (size_t)w * 4096 + l * 8;  // slice stride 2*4*512
    half8 a0[4], a1[4];
#pragma unroll
    for (int tn = 0; tn < 4; ++tn) {
      a0[tn] = *(const half8*)(wb + tn * 512);
      a1[tn] = *(const half8*)(wb + 2048 + tn * 512);
    }
    half8 bc0[8], bc1[8];
#pragma unroll
    for (int tm = 0; tm < 8; ++tm) bc0[tm] = *(const half8*)(ap + tm * 16 * AST);
#pragma unroll
    for (int tm = 0; tm < 8; ++tm) bc1[tm] = *(const half8*)(ap + tm * 16 * AST + 32);
#pragma unroll
    for (int tn = 0; tn < 4; ++tn) {
      float4_t bz = *(const float4_t*)(b0 + 64 * w + tn * 16 + q * 4);
#pragma unroll
      for (int tm = 0; tm < 8; ++tm) acc[tn][tm] = bz;
    }
#pragma unroll
    for (int tn = 0; tn < 4; ++tn)
#pragma unroll
      for (int tm = 0; tm < 8; ++tm)
        acc[tn][tm] = __builtin_amdgcn_mfma_f32_16x16x32_f16(a0[tn], bc0[tm], acc[tn][tm], 0, 0, 0);
#pragma unroll
    for (int tn = 0; tn < 4; ++tn)
#pragma unroll
      for (int tm = 0; tm < 8; ++tm)
        acc[tn][tm] = __builtin_amdgcn_mfma_f32_16x16x32_f16(a1[tn], bc1[tm], acc[tn][tm], 0, 0, 0);
  }
  __syncthreads();                                   // (2) all E reads done
#pragma unroll
  for (int tn = 0; tn < 4; ++tn)
#pragma unroll
    for (int tm = 0; tm < 8; ++tm) {
      float4_t v = acc[tn][tm];
      *(half4_t*)&actX[(tm * 16 + c) * AST + 64 * w + tn * 16 + q * 4] =
          pack4(v[0], v[1], v[2], v[3]);
    }
  __syncthreads();                                   // (3) h ready

  // ---- layer 1 (+ part head): masked kb pair FIRST, snapshot after j==1 ----
  {
    const _Float16* wb = W1sw + (size_t)w * 16384 + l * 8;  // slice stride 8*4*512
    const int w2 = 2 * w;
    float bcw = bc[w];
#pragma unroll
    for (int tn = 0; tn < 4; ++tn) {
      float4_t bz = *(const float4_t*)(b1 + 64 * w + tn * 16 + q * 4);
#pragma unroll
      for (int tm = 0; tm < 8; ++tm) acc[tn][tm] = bz;
    }
    auto kbof = [&](int j) {
      return (j < 2) ? (w2 + j) : ((j - 2) + ((j - 2) >= w2 ? 2 : 0));
    };
    half8 A[4][4];          // 4-buffer rotation: prefetch target != in-use
#pragma unroll
    for (int p = 0; p < 3; ++p) {
      const _Float16* pa = wb + kbof(p) * 2048;
#pragma unroll
      for (int tn = 0; tn < 4; ++tn) A[p][tn] = *(const half8*)(pa + tn * 512);
    }
    half8 bcur[8];
#pragma unroll
    for (int tm = 0; tm < 8; ++tm)
      bcur[tm] = *(const half8*)(ap + tm * 16 * AST + kbof(0) * 32);
#pragma unroll
    for (int j = 0; j < 8; ++j) {
      half8 bnxt[8];
      if (j + 1 < 8) {                       // issue B(kb+1) BEFORE MFMAs of kb
        const int kbn = kbof(j + 1);
#pragma unroll
        for (int tm = 0; tm < 8; ++tm)
          bnxt[tm] = *(const half8*)(ap + tm * 16 * AST + kbn * 32);
      }
      if (j + 3 < 8) {                       // issue A(kb+3) BEFORE MFMAs of kb
        const _Float16* pa = wb + kbof(j + 3) * 2048;
#pragma unroll
        for (int tn = 0; tn < 4; ++tn)
          A[(j + 3) & 3][tn] = *(const half8*)(pa + tn * 512);
      }
#pragma unroll
      for (int tn = 0; tn < 4; ++tn)
#pragma unroll
        for (int tm = 0; tm < 8; ++tm)
          acc[tn][tm] = __builtin_amdgcn_mfma_f32_16x16x32_f16(
              A[j & 3][tn], bcur[tm], acc[tn][tm], 0, 0, 0);
      if (j == 1) {
        // snapshot: acc = b1 + (x*mask_w) @ W1-slice -> class head for part w
        float pcls[8] = {0.f, 0.f, 0.f, 0.f, 0.f, 0.f, 0.f, 0.f};
#pragma unroll
        for (int tn = 0; tn < 4; ++tn) {
          float4_t wcv = *(const float4_t*)(Wc + 256 * w + 64 * w + tn * 16 + q * 4);
#pragma unroll
          for (int tm = 0; tm < 8; ++tm) {
            float4_t v = acc[tn][tm];
#pragma unroll
            for (int r = 0; r < 4; ++r) pcls[tm] += fmaxf(v[r], 0.f) * wcv[r];
          }
        }
#pragma unroll
        for (int tm = 0; tm < 8; ++tm) {
          float s = pcls[tm];
          s += __shfl_xor(s, 16, 64);
          s += __shfl_xor(s, 32, 64);
          if (l < 16)
            out[(size_t)NPTS + (size_t)(m0 + tm * 16 + c) * 4 + w] = s + bcw;
        }
      }
      if (j + 1 < 8) {
#pragma unroll
        for (int tm = 0; tm < 8; ++tm) bcur[tm] = bnxt[tm];   // renamed away (unrolled)
      }
    }
  }
  __syncthreads();                                   // (4) all h reads done
#pragma unroll
  for (int tn = 0; tn < 4; ++tn)
#pragma unroll
    for (int tm = 0; tm < 8; ++tm) {
      float4_t v = acc[tn][tm];
      *(half4_t*)&actX[(tm * 16 + c) * AST + 64 * w + tn * 16 + q * 4] =
          pack4(fmaxf(v[0], 0.f), fmaxf(v[1], 0.f), fmaxf(v[2], 0.f), fmaxf(v[3], 0.f));
    }
  __syncthreads();                                   // (5) t1 ready

  // ---- layer 2 + occ head ----
  {
    const _Float16* wb = W2sw + (size_t)w * 16384 + l * 8;
#pragma unroll
    for (int tn = 0; tn < 4; ++tn) {
      float4_t bz = *(const float4_t*)(b2 + 64 * w + tn * 16 + q * 4);
#pragma unroll
      for (int tm = 0; tm < 8; ++tm) acc[tn][tm] = bz;
    }
    half8 A[4][4];
#pragma unroll
    for (int p = 0; p < 3; ++p)
#pragma unroll
      for (int tn = 0; tn < 4; ++tn)
        A[p][tn] = *(const half8*)(wb + p * 2048 + tn * 512);
    half8 bcur[8];
#pragma unroll
    for (int tm = 0; tm < 8; ++tm) bcur[tm] = *(const half8*)(ap + tm * 16 * AST);
#pragma unroll
    for (int kb = 0; kb < 8; ++kb) {
      half8 bnxt[8];
      if (kb + 1 < 8) {
#pragma unroll
        for (int tm = 0; tm < 8; ++tm)
          bnxt[tm] = *(const half8*)(ap + tm * 16 * AST + (kb + 1) * 32);
      }
      if (kb + 3 < 8) {
#pragma unroll
        for (int tn = 0; tn < 4; ++tn)
          A[(kb + 3) & 3][tn] = *(const half8*)(wb + (kb + 3) * 2048 + tn * 512);
      }
#pragma unroll
      for (int tn = 0; tn < 4; ++tn)
#pragma unroll
        for (int tm = 0; tm < 8; ++tm)
          acc[tn][tm] = __builtin_amdgcn_mfma_f32_16x16x32_f16(
              A[kb & 3][tn], bcur[tm], acc[tn][tm], 0, 0, 0);
      if (kb + 1 < 8) {
#pragma unroll
        for (int tm = 0; tm < 8; ++tm) bcur[tm] = bnxt[tm];
      }
    }
    float pocc[8] = {0.f, 0.f, 0.f, 0.f, 0.f, 0.f, 0.f, 0.f};
#pragma unroll
    for (int tn = 0; tn < 4; ++tn) {
      float4_t wov = *(const float4_t*)(Wocc + 64 * w + tn * 16 + q * 4);
#pragma unroll
      for (int tm = 0; tm < 8; ++tm) {
        float4_t v = acc[tn][tm];
#pragma unroll
        for (int r = 0; r < 4; ++r) pocc[tm] += fmaxf(v[r], 0.f) * wov[r];
      }
    }
#pragma unroll
    for (int tm = 0; tm < 8; ++tm) {
      float s = pocc[tm];
      s += __shfl_xor(s, 16, 64);
      s += __shfl_xor(s, 32, 64);
      if (l < 16) occ_s[w][tm * 16 + c] = s;
    }
  }
  __syncthreads();                                   // (6) occ partials ready
  if (t < M_PB) {
    out[m0 + t] = occ_s[0][t] + occ_s[1][t] + occ_s[2][t] + occ_s[3][t] + bocc[0];
  }
}

extern "C" void kernel_launch(void* const* d_in, const int* in_sizes, int n_in,
                              void* d_out, int out_size, void* d_ws, size_t ws_size,
                              hipStream_t stream) {
  const float* coords = (const float*)d_in[0];
  const float* W0   = (const float*)d_in[1];
  const float* b0   = (const float*)d_in[2];
  const float* W1   = (const float*)d_in[3];
  const float* b1   = (const float*)d_in[4];
  const float* W2   = (const float*)d_in[5];
  const float* b2   = (const float*)d_in[6];
  const float* Wocc = (const float*)d_in[7];
  const float* bocc = (const float*)d_in[8];
  const float* Wc   = (const float*)d_in[9];
  const float* bc   = (const float*)d_in[10];
  float* out = (float*)d_out;

  _Float16* ws = (_Float16*)d_ws;       // W0sw[16384] | W1sw[65536] | W2sw[65536]
  _Float16* W0sw = ws;
  _Float16* W1sw = ws + 16384;
  _Float16* W2sw = ws + 81920;

  prep<<<576, 256, 0, stream>>>(W0, W1, W2, ws);
  mlp_main<<<NPTS / M_PB, 256, 0, stream>>>(coords, W0sw, W1sw, W2sw,
                                            b0, b1, b2, Wocc, bocc, Wc, bc, out);
}